// Round 6
// baseline (121.152 us; speedup 1.0000x reference)
//
#include <hip/hip_runtime.h>

// Inverse dyadic wavelet synthesis step (db4, circular boundary).
// out[r][2s]   = sum_{i=0..3} d[r][(s+i)%M]*g[2i]   + a[r][(s+i)%M]*h[2i]
// out[r][2s+1] = sum_{i=1..4} d[r][(s+i)%M]*g[2i-1] + a[r][(s+i)%M]*h[2i-1]
// h = scaling, g[k] = scaling[7-k] * (-1)^k
//
// R6: back to one-shot dispatch (persistent loop regressed). Fatter tile:
// 8 s-values per thread -> 16 outputs, 3 exact float4 loads per input
// (read amplification 2x -> 1.5x), 4 float4 stores. Halves per-byte
// instruction overhead, doubles per-thread MLP.

#define M_LEN 8192
#define N_ROWS 4096
#define S_PER_THREAD 8
#define THREADS_PER_ROW (M_LEN / S_PER_THREAD)   // 1024
#define NTHREADS 256

typedef float vfloat4 __attribute__((ext_vector_type(4)));

__global__ __launch_bounds__(NTHREADS) void idwt_db4_kernel(
    const float* __restrict__ det,
    const float* __restrict__ apx,
    const float* __restrict__ sc,
    float* __restrict__ out)
{
    const int gid = blockIdx.x * NTHREADS + threadIdx.x;
    const int row = gid >> 10;               // gid / 1024
    const int s0  = (gid & 1023) << 3;       // first s handled by this thread

    // filter: two vector loads (uniform address -> broadcast)
    const vfloat4 sv0 = *(const vfloat4*)(sc);
    const vfloat4 sv1 = *(const vfloat4*)(sc + 4);
    const float h0 = sv0.x, h1 = sv0.y, h2 = sv0.z, h3 = sv0.w;
    const float h4 = sv1.x, h5 = sv1.y, h6 = sv1.z, h7 = sv1.w;
    // g[k] = sc[7-k] * ((k & 1) ? -1 : 1)
    const float g0 =  h7, g1 = -h6, g2 =  h5, g3 = -h4;
    const float g4 =  h3, g5 = -h2, g6 =  h1, g7 = -h0;

    const float* __restrict__ dr = det + (size_t)row * M_LEN;
    const float* __restrict__ ar = apx + (size_t)row * M_LEN;

    float d[12], a[12];
    if (s0 + 12 <= M_LEN) {
        // fast path: three exact float4 loads per input
        const vfloat4 dv0 = *(const vfloat4*)(dr + s0);
        const vfloat4 dv1 = *(const vfloat4*)(dr + s0 + 4);
        const vfloat4 dv2 = *(const vfloat4*)(dr + s0 + 8);
        const vfloat4 av0 = *(const vfloat4*)(ar + s0);
        const vfloat4 av1 = *(const vfloat4*)(ar + s0 + 4);
        const vfloat4 av2 = *(const vfloat4*)(ar + s0 + 8);
        d[0] = dv0.x; d[1]  = dv0.y; d[2]  = dv0.z; d[3]  = dv0.w;
        d[4] = dv1.x; d[5]  = dv1.y; d[6]  = dv1.z; d[7]  = dv1.w;
        d[8] = dv2.x; d[9]  = dv2.y; d[10] = dv2.z; d[11] = dv2.w;
        a[0] = av0.x; a[1]  = av0.y; a[2]  = av0.z; a[3]  = av0.w;
        a[4] = av1.x; a[5]  = av1.y; a[6]  = av1.z; a[7]  = av1.w;
        a[8] = av2.x; a[9]  = av2.y; a[10] = av2.z; a[11] = av2.w;
    } else {
        // circular wrap: only the last thread of each row (1 per 1024)
#pragma unroll
        for (int i = 0; i < 12; ++i) {
            const int idx = (s0 + i) & (M_LEN - 1);
            d[i] = dr[idx];
            a[i] = ar[idx];
        }
    }

    float o[16];
#pragma unroll
    for (int k = 0; k < 8; ++k) {
        o[2*k]     = d[k]  * g0 + d[k+1] * g2 + d[k+2] * g4 + d[k+3] * g6
                   + a[k]  * h0 + a[k+1] * h2 + a[k+2] * h4 + a[k+3] * h6;
        o[2*k + 1] = d[k+1] * g1 + d[k+2] * g3 + d[k+3] * g5 + d[k+4] * g7
                   + a[k+1] * h1 + a[k+2] * h3 + a[k+3] * h5 + a[k+4] * h7;
    }

    float* __restrict__ orow = out + (size_t)row * (2 * M_LEN) + 2 * s0;
    *(vfloat4*)(orow)      = (vfloat4){ o[0],  o[1],  o[2],  o[3]  };
    *(vfloat4*)(orow + 4)  = (vfloat4){ o[4],  o[5],  o[6],  o[7]  };
    *(vfloat4*)(orow + 8)  = (vfloat4){ o[8],  o[9],  o[10], o[11] };
    *(vfloat4*)(orow + 12) = (vfloat4){ o[12], o[13], o[14], o[15] };
}

extern "C" void kernel_launch(void* const* d_in, const int* in_sizes, int n_in,
                              void* d_out, int out_size, void* d_ws, size_t ws_size,
                              hipStream_t stream) {
    const float* det = (const float*)d_in[0];   // details      (4096, 8192) f32
    const float* apx = (const float*)d_in[1];   // approximation(4096, 8192) f32
    const float* sc  = (const float*)d_in[2];   // scaling      (8,)         f32
    float* out = (float*)d_out;                 // (4096, 16384) f32

    const int total_threads = N_ROWS * THREADS_PER_ROW;   // 4,194,304
    const int blocks = total_threads / NTHREADS;           // 16,384

    idwt_db4_kernel<<<blocks, NTHREADS, 0, stream>>>(det, apx, sc, out);
}

// Round 7
// 98.261 us; speedup vs baseline: 1.2330x; 1.2330x over previous
//
#include <hip/hip_runtime.h>

// Inverse dyadic wavelet synthesis step (db4, circular boundary).
// out[r][2s]   = sum_{i=0..3} d[r][(s+i)%M]*g[2i]   + a[r][(s+i)%M]*h[2i]
// out[r][2s+1] = sum_{i=1..4} d[r][(s+i)%M]*g[2i-1] + a[r][(s+i)%M]*h[2i-1]
// h = scaling, g[k] = scaling[7-k] * (-1)^k
//
// R7: R0 compute + LDS-staged stores. R0's stores had 32B lane stride
// (half-coalesced: each 128B line written 64B at a time by 2 instructions).
// Stage o[8] in 8KB LDS, then store block-contiguous float4s (16B lane
// stride, full lines, 1KB/instruction). XOR swizzle (u ^= (u>>3)&1, an
// involution) keeps both LDS phases at the minimal bank pattern.

#define M_LEN 8192
#define N_ROWS 4096
#define NTHREADS 256
#define THREADS_PER_ROW (M_LEN / 4)   // 2048: 8 blocks per row, same-row blocks

typedef float vfloat4 __attribute__((ext_vector_type(4)));

__device__ __forceinline__ int swz(int u) { return u ^ ((u >> 3) & 1); }

__global__ __launch_bounds__(NTHREADS) void idwt_db4_kernel(
    const float* __restrict__ det,
    const float* __restrict__ apx,
    const float* __restrict__ sc,
    float* __restrict__ out)
{
    __shared__ vfloat4 lds[512];   // 8 KB: 256 threads x 8 output floats

    const int tid = threadIdx.x;
    const int gid = blockIdx.x * NTHREADS + tid;
    const int row = gid >> 11;               // gid / 2048
    const int s0  = (gid & 2047) << 2;       // first s handled by this thread

    // filter (uniform address -> scalar/broadcast loads)
    const vfloat4 sv0 = *(const vfloat4*)(sc);
    const vfloat4 sv1 = *(const vfloat4*)(sc + 4);
    const float h0 = sv0.x, h1 = sv0.y, h2 = sv0.z, h3 = sv0.w;
    const float h4 = sv1.x, h5 = sv1.y, h6 = sv1.z, h7 = sv1.w;
    // g[k] = sc[7-k] * ((k & 1) ? -1 : 1)
    const float g0 =  h7, g1 = -h6, g2 =  h5, g3 = -h4;
    const float g4 =  h3, g5 = -h2, g6 =  h1, g7 = -h0;

    const float* __restrict__ dr = det + (size_t)row * M_LEN;
    const float* __restrict__ ar = apx + (size_t)row * M_LEN;

    float d[8], a[8];
    if (s0 + 8 <= M_LEN) {
        // loads: lane stride 16B -> fully coalesced (1KB/instruction)
        const vfloat4 dv0 = *(const vfloat4*)(dr + s0);
        const vfloat4 dv1 = *(const vfloat4*)(dr + s0 + 4);
        const vfloat4 av0 = *(const vfloat4*)(ar + s0);
        const vfloat4 av1 = *(const vfloat4*)(ar + s0 + 4);
        d[0] = dv0.x; d[1] = dv0.y; d[2] = dv0.z; d[3] = dv0.w;
        d[4] = dv1.x; d[5] = dv1.y; d[6] = dv1.z; d[7] = dv1.w;
        a[0] = av0.x; a[1] = av0.y; a[2] = av0.z; a[3] = av0.w;
        a[4] = av1.x; a[5] = av1.y; a[6] = av1.z; a[7] = av1.w;
    } else {
        // circular wrap: only block-local tid==255 of every 8th block
#pragma unroll
        for (int i = 0; i < 8; ++i) {
            const int idx = (s0 + i) & (M_LEN - 1);
            d[i] = dr[idx];
            a[i] = ar[idx];
        }
    }

    float o[8];
#pragma unroll
    for (int k = 0; k < 4; ++k) {
        o[2*k]     = d[k]  * g0 + d[k+1] * g2 + d[k+2] * g4 + d[k+3] * g6
                   + a[k]  * h0 + a[k+1] * h2 + a[k+2] * h4 + a[k+3] * h6;
        o[2*k + 1] = d[k+1] * g1 + d[k+2] * g3 + d[k+3] * g5 + d[k+4] * g7
                   + a[k+1] * h1 + a[k+2] * h3 + a[k+3] * h5 + a[k+4] * h7;
    }

    // stage outputs: logical 16B unit u holds block-local floats [4u, 4u+4)
    const int u0 = 2 * tid;
    const int u1 = 2 * tid + 1;
    lds[swz(u0)] = (vfloat4){ o[0], o[1], o[2], o[3] };
    lds[swz(u1)] = (vfloat4){ o[4], o[5], o[6], o[7] };
    __syncthreads();

    // block covers out floats [blockIdx*2048, +2048) = 512 contiguous units
    vfloat4* __restrict__ outv = (vfloat4*)out + (size_t)blockIdx.x * 512;
    outv[tid]       = lds[swz(tid)];         // part 0: units [0,256)
    outv[256 + tid] = lds[swz(256 + tid)];   // part 1: units [256,512)
}

extern "C" void kernel_launch(void* const* d_in, const int* in_sizes, int n_in,
                              void* d_out, int out_size, void* d_ws, size_t ws_size,
                              hipStream_t stream) {
    const float* det = (const float*)d_in[0];   // details      (4096, 8192) f32
    const float* apx = (const float*)d_in[1];   // approximation(4096, 8192) f32
    const float* sc  = (const float*)d_in[2];   // scaling      (8,)         f32
    float* out = (float*)d_out;                 // (4096, 16384) f32

    const int total_threads = N_ROWS * THREADS_PER_ROW;   // 8,388,608
    const int blocks = total_threads / NTHREADS;           // 32,768

    idwt_db4_kernel<<<blocks, NTHREADS, 0, stream>>>(det, apx, sc, out);
}